// Round 11
// baseline (158.054 us; speedup 1.0000x reference)
//
#include <hip/hip_runtime.h>
#include <hip/hip_bf16.h>
#include <math.h>

#define BB 16
#define CC 3
#define HH 336
#define WW 1078
#define HW (HH * WW)

#define TX 128          // output tile width
#define TY 8            // output tile height
#define NBX 9           // ceil(1078/128)
#define NBY 42          // 336/8
#define WX 176          // staged window cols (span <= ~154 worst case + slack)
#define WY 28           // staged window rows (span <= ~20 + slack)
#define NBLK (NBX * NBY * BB)   // 6048 blocks

typedef float v4f __attribute__((ext_vector_type(4)));

// ---------------------------------------------------------------------------
// Kernel 1: closed-form DLT (verified R5+: out of top-5; was 71 us as
// scratch-spilling 8x8 GE).
// ---------------------------------------------------------------------------
__global__ void homography_kernel(const float* __restrict__ src_pt,
                                  const float* __restrict__ dst_pt,
                                  float* __restrict__ Hout) {
    int b = threadIdx.x;
    if (b >= BB) return;

    const float* s = src_pt + b * 8;
    const float* d = dst_pt + b * 8;
    double a  = (double)s[2];
    double bb = (double)s[5];
    double u0 = d[0], v0 = d[1], u1 = d[2], v1 = d[3];
    double u2 = d[4], v2 = d[5], u3 = d[6], v3 = d[7];

    double A11 = a  * (u1 - u3), A12 = bb * (u2 - u3), r1 = u0 - u1 - u2 + u3;
    double A21 = a  * (v1 - v3), A22 = bb * (v2 - v3), r2 = v0 - v1 - v2 + v3;
    double det = A11 * A22 - A12 * A21;
    double inv = 1.0 / det;
    double h6 = (r1 * A22 - A12 * r2) * inv;
    double h7 = (A11 * r2 - A21 * r1) * inv;

    double h0 = (u1 - u0) / a  + u1 * h6;
    double h1 = (u2 - u0) / bb + u2 * h7;
    double h3 = (v1 - v0) / a  + v1 * h6;
    double h4 = (v2 - v0) / bb + v2 * h7;

    float* Ho = Hout + b * 9;
    Ho[0] = (float)h0; Ho[1] = (float)h1; Ho[2] = (float)u0;
    Ho[3] = (float)h3; Ho[4] = (float)h4; Ho[5] = (float)v0;
    Ho[6] = (float)h6; Ho[7] = (float)h7; Ho[8] = 1.0f;
}

// ---------------------------------------------------------------------------
// Kernel 2: LDS-staged bilinear warp. R10 diagnosis: time flat ~42-46 us
// across 1/2/4 px/thread = vmem-instruction-throughput-bound (12 gather
// loads + 3 stores per px invariant). Fix: stage the 176x28 source window
// per (block, channel) into LDS with coalesced float4 loads, take the 12
// taps from LDS (ds_read_b32, conflict-free: row stride 176 = 16 mod 32
// banks). Global vmem/px: 15 -> ~4. Pixel math identical to validated R8
// path (rcp included). Window from tile-corner transforms + margin 3 +
// defensive offset clamps; border blocks use scalar-clamped staging.
// ---------------------------------------------------------------------------
__global__ __launch_bounds__(256) void warp_kernel(const float* __restrict__ src,
                                                   const float* __restrict__ Hbuf,
                                                   float* __restrict__ out) {
    __shared__ float lds[WY * WX];

    int blk = blockIdx.x;
    int bx = blk % NBX;
    int by = (blk / NBX) % NBY;
    int b  = blk / (NBX * NBY);
    int X0 = bx * TX, Y0 = by * TY;
    int tid = threadIdx.x;
    int tx = tid & 31, ty = tid >> 5;

    const float* Hm = Hbuf + b * 9;
    float H0 = Hm[0], H1 = Hm[1], H2 = Hm[2];
    float H3 = Hm[3], H4 = Hm[4], H5 = Hm[5];
    float H6 = Hm[6], H7 = Hm[7], H8 = Hm[8];

    // ---- source window from the 4 tile corners (block-uniform) ----
    float minx = 1e30f, miny = 1e30f;
    #pragma unroll
    for (int cy = 0; cy < 2; ++cy) {
        #pragma unroll
        for (int cx = 0; cx < 2; ++cx) {
            float gx = (float)(X0 + cx * (TX - 1));
            float gy = (float)(Y0 + cy * (TY - 1));
            float X = H0 * gx + H1 * gy + H2;
            float Y = H3 * gx + H4 * gy + H5;
            float T = H6 * gx + H7 * gy + H8;
            if (!(fabsf(T) >= 1e-7f)) T += 1e-6f;
            float rT = __builtin_amdgcn_rcpf(T);
            minx = fminf(minx, X * rT);
            miny = fminf(miny, Y * rT);
        }
    }
    int cx0  = (((int)floorf(minx)) - 3) & ~3;   // 16B-aligned window start
    int rmin = ((int)floorf(miny)) - 3;

    // ---- per-pixel coords, reference-exact (4 px: x = X0+tx+32k) ----
    float w0[4], w1[4], w2[4], w3[4];
    int oa[4], obi[4], oc[4], od[4];
    int gyi = Y0 + ty;
    float gy = (float)gyi;
    #pragma unroll
    for (int k = 0; k < 4; ++k) {
        float gx = (float)(X0 + tx + 32 * k);
        float X = H0 * gx + H1 * gy + H2;
        float Y = H3 * gx + H4 * gy + H5;
        float T = H6 * gx + H7 * gy + H8;
        if (!(fabsf(T) >= 1e-7f)) T += 1e-6f;
        float rT = __builtin_amdgcn_rcpf(T);
        float x = X * rT;
        float y = Y * rT;

        float fx = floorf(x), fy = floorf(y);
        float x0 = fminf(fmaxf(fx,        0.0f), (float)(WW - 1));
        float x1 = fminf(fmaxf(fx + 1.0f, 0.0f), (float)(WW - 1));
        float y0 = fminf(fmaxf(fy,        0.0f), (float)(HH - 1));
        float y1 = fminf(fmaxf(fy + 1.0f, 0.0f), (float)(HH - 1));

        w0[k] = (x1 - x) * (y1 - y);
        w1[k] = (x1 - x) * (y - y0);
        w2[k] = (x - x0) * (y1 - y);
        w3[k] = (x - x0) * (y - y0);

        int ir0 = min(max((int)y0 - rmin, 0), WY - 1);
        int ir1 = min(max((int)y1 - rmin, 0), WY - 1);
        int ic0 = min(max((int)x0 - cx0,  0), WX - 1);
        int ic1 = min(max((int)x1 - cx0,  0), WX - 1);
        oa[k]  = ir0 * WX + ic0;
        obi[k] = ir1 * WX + ic0;
        oc[k]  = ir0 * WX + ic1;
        od[k]  = ir1 * WX + ic1;
    }

    bool interior = (cx0 >= 0) && (cx0 + WX <= WW) &&
                    (rmin >= 0) && (rmin + WY <= HH);
    const float* sb = src + b * CC * HW;
    float* obp = out + b * CC * HW + gyi * WW + X0 + tx;

    for (int ch = 0; ch < CC; ++ch) {
        if (ch) __syncthreads();           // prior compute done before overwrite
        const float* sp = sb + ch * HW;

        // ---- stage window (44 float4-cols x 28 rows = 1232 quads) ----
        if (interior) {
            for (int i = tid; i < (WX / 4) * WY; i += 256) {
                int r  = i / (WX / 4);
                int c4 = (i - r * (WX / 4)) * 4;
                v4f v;
                __builtin_memcpy(&v, sp + (rmin + r) * WW + cx0 + c4, 16);
                __builtin_memcpy(&lds[r * WX + c4], &v, 16);
            }
        } else {
            for (int i = tid; i < (WX / 4) * WY; i += 256) {
                int r  = i / (WX / 4);
                int c4 = (i - r * (WX / 4)) * 4;
                int gr = min(max(rmin + r, 0), HH - 1);
                #pragma unroll
                for (int j = 0; j < 4; ++j) {
                    int gc = min(max(cx0 + c4 + j, 0), WW - 1);
                    lds[r * WX + c4 + j] = sp[gr * WW + gc];
                }
            }
        }
        __syncthreads();

        // ---- 4 px from LDS + store ----
        #pragma unroll
        for (int k = 0; k < 4; ++k) {
            float v = w0[k] * lds[oa[k]] + w1[k] * lds[obi[k]]
                    + w2[k] * lds[oc[k]] + w3[k] * lds[od[k]];
            int gx = X0 + tx + 32 * k;
            if (gx < WW) obp[ch * HW + 32 * k] = v;
        }
    }
}

extern "C" void kernel_launch(void* const* d_in, const int* in_sizes, int n_in,
                              void* d_out, int out_size, void* d_ws, size_t ws_size,
                              hipStream_t stream) {
    const float* src    = (const float*)d_in[0];
    const float* src_pt = (const float*)d_in[1];
    const float* dst_pt = (const float*)d_in[2];
    float* out = (float*)d_out;
    float* Hbuf = (float*)d_ws;  // 16 * 9 floats

    homography_kernel<<<1, 64, 0, stream>>>(src_pt, dst_pt, Hbuf);
    warp_kernel<<<NBLK, 256, 0, stream>>>(src, Hbuf, out);
}

// Round 16
// 138.363 us; speedup vs baseline: 1.1423x; 1.1423x over previous
//
#include <hip/hip_runtime.h>
#include <hip/hip_bf16.h>
#include <math.h>

#define BB 16
#define CC 3
#define HH 336
#define WW 1078
#define HW (HH * WW)
#define TPR (WW / 2)           // 539: thread t covers x=xi2 and x=xi2+539
#define NROWS (BB * HH)        // 5376
#define NTHREADS (NROWS * TPR) // 2,897,664 = 11,319 * 256 exactly
#define NBLK (NTHREADS / 256)  // 11,319 = 8*1414 + 7

// ---------------------------------------------------------------------------
// Kernel 1: closed-form DLT for the corner-rectangle case (verified R5+:
// out of top-5 dispatches; was 71 us as scratch-spilling 8x8 GE).
// ---------------------------------------------------------------------------
__global__ void homography_kernel(const float* __restrict__ src_pt,
                                  const float* __restrict__ dst_pt,
                                  float* __restrict__ Hout) {
    int b = threadIdx.x;
    if (b >= BB) return;

    const float* s = src_pt + b * 8;
    const float* d = dst_pt + b * 8;
    double a  = (double)s[2];   // x of corner 1  (W-1)
    double bb = (double)s[5];   // y of corner 2  (H-1)
    double u0 = d[0], v0 = d[1], u1 = d[2], v1 = d[3];
    double u2 = d[4], v2 = d[5], u3 = d[6], v3 = d[7];

    double A11 = a  * (u1 - u3), A12 = bb * (u2 - u3), r1 = u0 - u1 - u2 + u3;
    double A21 = a  * (v1 - v3), A22 = bb * (v2 - v3), r2 = v0 - v1 - v2 + v3;
    double det = A11 * A22 - A12 * A21;
    double inv = 1.0 / det;
    double h6 = (r1 * A22 - A12 * r2) * inv;
    double h7 = (A11 * r2 - A21 * r1) * inv;

    double h0 = (u1 - u0) / a  + u1 * h6;
    double h1 = (u2 - u0) / bb + u2 * h7;
    double h3 = (v1 - v0) / a  + v1 * h6;
    double h4 = (v2 - v0) / bb + v2 * h7;

    float* Ho = Hout + b * 9;
    Ho[0] = (float)h0; Ho[1] = (float)h1; Ho[2] = (float)u0;
    Ho[3] = (float)h3; Ho[4] = (float)h4; Ho[5] = (float)v0;
    Ho[6] = (float)h6; Ho[7] = (float)h7; Ho[8] = 1.0f;
}

// ---------------------------------------------------------------------------
// Kernel 2: bilinear homography warp — the R6 kernel (best: 41.7 us) with ONE
// change: bijective chunked XCD swizzle (m204 form). Hardware assigns
// blockIdx round-robin to XCDs; un-swizzled, adjacent output rows (which
// share source tap-rows) land on different non-coherent L2s -> boundary rows
// fetched multiple times from HBM (FETCH 86.7 MB vs 69.5 ideal). Swizzle
// gives each XCD a contiguous (batch,row) chunk (~2 whole images) so every
// source line is fetched by exactly one L2.
// Structure: 2 px/thread far-split (xi2, xi2+539) -> consecutive lanes access
// consecutive addresses for every tap (R6 lesson); 12 aligned 4B tap loads
// per thread-pixel-pair (R8 lesson: beats unaligned 8B pairs); rcp for
// the divide (validated R8: absmax identical).
// ---------------------------------------------------------------------------
__global__ __launch_bounds__(256) void warp_kernel(const float* __restrict__ src,
                                                   const float* __restrict__ Hbuf,
                                                   float* __restrict__ out) {
    // Bijective chunked XCD swizzle: nblk = 11319 = 8*1414 + 7 (q=1414, r=7).
    // Physical XCD of a block is ~ blockIdx%8; give that XCD the contiguous
    // work-chunk: xcd<r -> chunks of q+1, else q.
    int blk = blockIdx.x;
    int xcd = blk & 7;
    int pos = blk >> 3;
    int swz = (xcd < 7 ? xcd * 1415 : 7 * 1415 + (xcd - 7) * 1414) + pos;

    int t = swz * 256 + threadIdx.x;   // grid is exact, no tail
    int xi2 = t % TPR;
    int row = t / TPR;
    int yi = row % HH;
    int b  = row / HH;

    const float* Hm = Hbuf + b * 9;
    float H0 = Hm[0], H1 = Hm[1], H2 = Hm[2];
    float H3 = Hm[3], H4 = Hm[4], H5 = Hm[5];
    float H6 = Hm[6], H7 = Hm[7], H8 = Hm[8];

    float gy = (float)yi;
    float Xy = H1 * gy + H2;
    float Yy = H4 * gy + H5;
    float Ty = H7 * gy + H8;

    const float* sb = src + b * CC * HW;
    float res[2][CC];

    #pragma unroll
    for (int j = 0; j < 2; ++j) {
        float gx = (float)(xi2 + j * TPR);
        float X = H0 * gx + Xy;
        float Y = H3 * gx + Yy;
        float T = H6 * gx + Ty;
        if (!(fabsf(T) >= 1e-7f)) T += 1e-6f;
        float rT = __builtin_amdgcn_rcpf(T);
        float x = X * rT;
        float y = Y * rT;

        float fx = floorf(x), fy = floorf(y);
        float x0 = fminf(fmaxf(fx,        0.0f), (float)(WW - 1));
        float x1 = fminf(fmaxf(fx + 1.0f, 0.0f), (float)(WW - 1));
        float y0 = fminf(fmaxf(fy,        0.0f), (float)(HH - 1));
        float y1 = fminf(fmaxf(fy + 1.0f, 0.0f), (float)(HH - 1));

        float wa = (x1 - x) * (y1 - y);
        float wb = (x1 - x) * (y - y0);
        float wc = (x - x0) * (y1 - y);
        float wd = (x - x0) * (y - y0);

        int ix0 = (int)x0, ix1 = (int)x1, iy0 = (int)y0, iy1 = (int)y1;
        int o00 = iy0 * WW + ix0;
        int o10 = iy1 * WW + ix0;
        int o01 = iy0 * WW + ix1;
        int o11 = iy1 * WW + ix1;

        #pragma unroll
        for (int c = 0; c < CC; ++c) {
            const float* sc = sb + c * HW;
            res[j][c] = wa * sc[o00] + wb * sc[o10] + wc * sc[o01] + wd * sc[o11];
        }
    }

    float* ob = out + b * CC * HW + yi * WW + xi2;
    #pragma unroll
    for (int c = 0; c < CC; ++c) {
        ob[c * HW]       = res[0][c];
        ob[c * HW + TPR] = res[1][c];
    }
}

extern "C" void kernel_launch(void* const* d_in, const int* in_sizes, int n_in,
                              void* d_out, int out_size, void* d_ws, size_t ws_size,
                              hipStream_t stream) {
    const float* src    = (const float*)d_in[0];
    const float* src_pt = (const float*)d_in[1];
    const float* dst_pt = (const float*)d_in[2];
    float* out = (float*)d_out;
    float* Hbuf = (float*)d_ws;  // 16 * 9 floats

    homography_kernel<<<1, 64, 0, stream>>>(src_pt, dst_pt, Hbuf);
    warp_kernel<<<NBLK, 256, 0, stream>>>(src, Hbuf, out);
}